// Round 1
// baseline (512.704 us; speedup 1.0000x reference)
//
#include <hip/hip_runtime.h>
#include <hip/hip_bf16.h>

#define N_NODES 100000
#define N_EDGES 1000000
#define EPS 1e-5f
#define SLOPE 0.1f

__device__ __forceinline__ float bcast(float v, int l) {
  return __uint_as_float(__builtin_amdgcn_readlane(__float_as_uint(v), (unsigned)l));
}

__device__ __forceinline__ float lrelu(float v) { return v > 0.f ? v : SLOPE * v; }

// ---- node layer 1: h = leaky_relu(x @ W1n + b1n), stored bf16 [N,128]
__global__ __launch_bounds__(256) void node_l1(const float* __restrict__ x,
                                               const float* __restrict__ W1n,
                                               const float* __restrict__ b1n,
                                               __hip_bfloat16* __restrict__ h) {
  const int lane = threadIdx.x & 63;
  const int wid = (blockIdx.x * blockDim.x + threadIdx.x) >> 6;
  const int nw = (gridDim.x * blockDim.x) >> 6;
  float wa[64], wb[64];
#pragma unroll
  for (int k = 0; k < 64; ++k) {
    wa[k] = W1n[k * 128 + lane];
    wb[k] = W1n[k * 128 + lane + 64];
  }
  const float ba = b1n[lane], bb = b1n[lane + 64];
  for (int n = wid; n < N_NODES; n += nw) {
    const float xr = x[(size_t)n * 64 + lane];
    float ha = ba, hb = bb;
#pragma unroll
    for (int k = 0; k < 64; ++k) {
      const float xv = bcast(xr, k);
      ha = fmaf(xv, wa[k], ha);
      hb = fmaf(xv, wb[k], hb);
    }
    h[(size_t)n * 128 + lane] = __float2bfloat16(lrelu(ha));
    h[(size_t)n * 128 + 64 + lane] = __float2bfloat16(lrelu(hb));
  }
}

// ---- node layer 2: x_t = h @ W2n + b2n, stored bf16 [N,64]
__global__ __launch_bounds__(256) void node_l2(const __hip_bfloat16* __restrict__ h,
                                               const float* __restrict__ W2n,
                                               const float* __restrict__ b2n,
                                               __hip_bfloat16* __restrict__ xt) {
  const int lane = threadIdx.x & 63;
  const int wid = (blockIdx.x * blockDim.x + threadIdx.x) >> 6;
  const int nw = (gridDim.x * blockDim.x) >> 6;
  float w2[128];
#pragma unroll
  for (int k = 0; k < 128; ++k) w2[k] = W2n[k * 64 + lane];
  const float b = b2n[lane];
  for (int n = wid; n < N_NODES; n += nw) {
    // lane m holds h[2m], h[2m+1] (one dword load of two bf16)
    const unsigned hp = ((const unsigned*)h)[(size_t)n * 64 + lane];
    const float h0 = __uint_as_float(hp << 16);
    const float h1 = __uint_as_float(hp & 0xffff0000u);
    float acc = b;
#pragma unroll
    for (int m = 0; m < 64; ++m) {
      acc = fmaf(bcast(h0, m), w2[2 * m], acc);
      acc = fmaf(bcast(h1, m), w2[2 * m + 1], acc);
    }
    xt[(size_t)n * 64 + lane] = __float2bfloat16(acc);
  }
}

// ---- fused edge pipeline: e_t = mlp(edge_attr); msg = x_t[src]*e_t*dp; agg[dst] += msg
__global__ __launch_bounds__(256) void edge_fused(const float* __restrict__ ea_g,
                                                  const int* __restrict__ ei,
                                                  const float* __restrict__ W1e,
                                                  const float* __restrict__ b1e,
                                                  const float* __restrict__ W2e,
                                                  const float* __restrict__ b2e,
                                                  const __hip_bfloat16* __restrict__ xt,
                                                  const float* __restrict__ dp_scale,
                                                  float* __restrict__ agg) {
  const int lane = threadIdx.x & 63;
  const int wid = (blockIdx.x * blockDim.x + threadIdx.x) >> 6;
  const int nw = (gridDim.x * blockDim.x) >> 6;
  float w1[32], w2[64];
#pragma unroll
  for (int k = 0; k < 32; ++k) w1[k] = W1e[k * 64 + lane];
#pragma unroll
  for (int k = 0; k < 64; ++k) w2[k] = W2e[k * 64 + lane];
  const float b1 = b1e[lane], b2 = b2e[lane];
  const float scale = dp_scale[0];
  for (int e = wid; e < N_EDGES; e += nw) {
    const int src = ei[e];
    const int dst = ei[N_EDGES + e];
    const float ear = ea_g[(size_t)e * 32 + (lane & 31)];
    float hv = b1;
#pragma unroll
    for (int k = 0; k < 32; ++k) hv = fmaf(bcast(ear, k), w1[k], hv);
    hv = lrelu(hv);
    float et = b2;
#pragma unroll
    for (int k = 0; k < 64; ++k) et = fmaf(bcast(hv, k), w2[k], et);
    const float xs = __bfloat162float(xt[(size_t)src * 64 + lane]);
    unsafeAtomicAdd(&agg[(size_t)dst * 64 + lane], xs * et * scale);
  }
}

// ---- residual + LayerNorm, in place on d_out (which holds the aggregate)
__global__ __launch_bounds__(256) void finalize(const float* __restrict__ x,
                                                const float* __restrict__ res_w,
                                                const float* __restrict__ gamma,
                                                const float* __restrict__ beta,
                                                float* __restrict__ out) {
  const int lane = threadIdx.x & 63;
  const int wid = (blockIdx.x * blockDim.x + threadIdx.x) >> 6;
  const int nw = (gridDim.x * blockDim.x) >> 6;
  const float rw = res_w[0];
  const float g = gamma[lane], bb = beta[lane];
  for (int n = wid; n < N_NODES; n += nw) {
    float v = fmaf(out[(size_t)n * 64 + lane], rw, x[(size_t)n * 64 + lane]);
    float s = v;
#pragma unroll
    for (int off = 1; off < 64; off <<= 1) s += __shfl_xor(s, off);
    const float mu = s * (1.f / 64.f);
    const float d = v - mu;
    float s2 = d * d;
#pragma unroll
    for (int off = 1; off < 64; off <<= 1) s2 += __shfl_xor(s2, off);
    out[(size_t)n * 64 + lane] = fmaf(d * rsqrtf(s2 * (1.f / 64.f) + EPS), g, bb);
  }
}

extern "C" void kernel_launch(void* const* d_in, const int* in_sizes, int n_in,
                              void* d_out, int out_size, void* d_ws, size_t ws_size,
                              hipStream_t stream) {
  const float* x = (const float*)d_in[0];
  const float* edge_attr = (const float*)d_in[1];
  const float* W1n = (const float*)d_in[2];
  const float* b1n = (const float*)d_in[3];
  const float* W2n = (const float*)d_in[4];
  const float* b2n = (const float*)d_in[5];
  const float* W1e = (const float*)d_in[6];
  const float* b1e = (const float*)d_in[7];
  const float* W2e = (const float*)d_in[8];
  const float* b2e = (const float*)d_in[9];
  const float* res_w = (const float*)d_in[10];
  const float* dp_scale = (const float*)d_in[11];
  const float* gamma = (const float*)d_in[12];
  const float* beta = (const float*)d_in[13];
  const int* edge_index = (const int*)d_in[14];
  float* out = (float*)d_out;

  __hip_bfloat16* h = (__hip_bfloat16*)d_ws;                             // N*128 bf16
  __hip_bfloat16* xt = (__hip_bfloat16*)d_ws + (size_t)N_NODES * 128;    // N*64  bf16

  hipMemsetAsync(d_out, 0, (size_t)out_size * sizeof(float), stream);
  node_l1<<<1024, 256, 0, stream>>>(x, W1n, b1n, h);
  node_l2<<<1024, 256, 0, stream>>>(h, W2n, b2n, xt);
  edge_fused<<<2048, 256, 0, stream>>>(edge_attr, edge_index, W1e, b1e, W2e, b2e,
                                       xt, dp_scale, out);
  finalize<<<1024, 256, 0, stream>>>(x, res_w, gamma, beta, out);
}